// Round 1
// baseline (181.047 us; speedup 1.0000x reference)
//
#include <hip/hip_runtime.h>
#include <hip/hip_bf16.h>
#include <math.h>

// Problem constants (from reference): N=10000, E=50000, D=32, H=4, DH=8
#define DD 32
#define HH 4

__device__ __forceinline__ void atomicMaxFloat(float* addr, float val) {
    // sign-split trick; addr must be initialized to -inf
    if (val >= 0.0f) {
        atomicMax((int*)addr, __float_as_int(val));
    } else {
        atomicMin((unsigned int*)addr, __float_as_uint(val));
    }
}

// ---------------- Kernel A: per-edge linear + score -----------------
// One block (256 threads) per edge. tid = r*8 + t, r in [0,32): output row
// (h*8+dh), t in [0,8): column quarter. Each thread loads float4 of each
// weight row -> coalesced 16KB/block stream from HBM.
__global__ __launch_bounds__(256) void edge_kernel(
    const float* __restrict__ in_feat,  // [N,32]
    const float* __restrict__ query,    // [N,32]
    const float* __restrict__ skw, const float* __restrict__ dkw,
    const float* __restrict__ skb, const float* __restrict__ dkb,
    const float* __restrict__ svw, const float* __restrict__ dvw,
    const float* __restrict__ svb, const float* __restrict__ dvb,
    const int* __restrict__ src, const int* __restrict__ dst,
    float* __restrict__ Kout,   // [E,32] (d_out chunk 1)
    float* __restrict__ Vout,   // [E,32] (d_out chunk 2)
    float* __restrict__ score,  // [E,4]  (workspace)
    int E)
{
    const int e = blockIdx.x;
    if (e >= E) return;
    const int tid = threadIdx.x;
    const int r = tid >> 3;   // 0..31
    const int t = tid & 7;    // 0..7

    const int s = src[e];
    const int d = dst[e];

    const float4 u4 = *(const float4*)(in_feat + (size_t)s * DD + t * 4);
    const float4 v4 = *(const float4*)(in_feat + (size_t)d * DD + t * 4);

    const size_t woff = (size_t)e * 1024 + (size_t)r * 32 + (size_t)t * 4;

    float4 a = *(const float4*)(skw + woff);
    float4 b = *(const float4*)(dkw + woff);
    float pk = a.x * u4.x + a.y * u4.y + a.z * u4.z + a.w * u4.w
             + b.x * v4.x + b.y * v4.y + b.z * v4.z + b.w * v4.w;

    float4 c = *(const float4*)(svw + woff);
    float4 g = *(const float4*)(dvw + woff);
    float pv = c.x * u4.x + c.y * u4.y + c.z * u4.z + c.w * u4.w
             + g.x * v4.x + g.y * v4.y + g.z * v4.z + g.w * v4.w;

    // reduce over the 8 column-lanes (contiguous lanes within groups of 8)
    #pragma unroll
    for (int m = 1; m <= 4; m <<= 1) {
        pk += __shfl_xor(pk, m);
        pv += __shfl_xor(pv, m);
    }

    float kval = 0.0f, q = 0.0f;
    if (t == 0) {
        const size_t bo = (size_t)e * DD + r;
        kval = pk + skb[bo] + dkb[bo];
        float vval = pv + svb[bo] + dvb[bo];
        Kout[bo] = kval;
        Vout[bo] = vval;
        q = query[(size_t)d * DD + r];
    }
    // score_h = sum_dh K[h,dh]*q[h,dh]; wave w holds rows 8w..8w+7 (head w)
    float prod = kval * q;   // zero on t!=0 lanes
    #pragma unroll
    for (int m = 8; m <= 32; m <<= 1) prod += __shfl_xor(prod, m);
    if ((tid & 63) == 0) {
        const int h = tid >> 6;   // wave id == head id
        score[(size_t)e * HH + h] = prod;
    }
}

// ---------------- Kernel B1: init workspace ----------------
__global__ void init_kernel(float* __restrict__ smax, float* __restrict__ ssum,
                            float* __restrict__ agg, int NH, int ND)
{
    const int i = blockIdx.x * blockDim.x + threadIdx.x;
    if (i < NH) {
        smax[i] = __int_as_float(0xff800000);  // -inf
        ssum[i] = 0.0f;
    }
    if (i < ND) agg[i] = 0.0f;
}

// ---------------- Kernel B2: segment max ----------------
__global__ void smax_kernel(const float* __restrict__ score,
                            const int* __restrict__ dst,
                            float* __restrict__ smax, int EH)
{
    const int i = blockIdx.x * blockDim.x + threadIdx.x;
    if (i >= EH) return;
    const int e = i >> 2, h = i & 3;
    atomicMaxFloat(&smax[(size_t)dst[e] * HH + h], score[i]);
}

// ---------------- Kernel B3: exp + segment sum ----------------
__global__ void esum_kernel(const float* __restrict__ score,
                            const int* __restrict__ dst,
                            const float* __restrict__ smax,
                            float* __restrict__ ex, float* __restrict__ ssum,
                            int EH)
{
    const int i = blockIdx.x * blockDim.x + threadIdx.x;
    if (i >= EH) return;
    const int e = i >> 2, h = i & 3;
    const int d = dst[e];
    const float x = expf(score[i] - smax[(size_t)d * HH + h]);
    ex[i] = x;
    atomicAdd(&ssum[(size_t)d * HH + h], x);
}

// ---------------- Kernel B4: attn + weighted scatter-sum ----------------
__global__ void attn_agg_kernel(const float* __restrict__ ex,
                                const float* __restrict__ ssum,
                                const int* __restrict__ dst,
                                const float* __restrict__ V,     // [E,32]
                                float* __restrict__ attn_out,    // [E,4]
                                float* __restrict__ agg,         // [N,32]
                                int ED)
{
    const int i = blockIdx.x * blockDim.x + threadIdx.x;
    if (i >= ED) return;
    const int e = i >> 5, c = i & 31, h = c >> 3;
    const int d = dst[e];
    const float a = ex[(size_t)e * HH + h] / ssum[(size_t)d * HH + h];
    if ((c & 7) == 0) attn_out[(size_t)e * HH + h] = a;
    atomicAdd(&agg[(size_t)d * DD + c], V[i] * a);
}

// ---------------- Kernel C: node linear + relu + residual + LN ----------------
__global__ __launch_bounds__(256) void node_kernel(
    const float* __restrict__ in_feat,  // [N,32]
    const float* __restrict__ node_w,   // [N,32,32]
    const float* __restrict__ node_b,   // [N,32]
    const float* __restrict__ agg,      // [N,32]
    const float* __restrict__ ln_g, const float* __restrict__ ln_b,
    float* __restrict__ out, int N)
{
    __shared__ float ys[DD];
    const int n = blockIdx.x;
    if (n >= N) return;
    const int tid = threadIdx.x;
    const int r = tid >> 3, t = tid & 7;

    const float4 a4 = *(const float4*)(agg + (size_t)n * DD + t * 4);
    const float4 w4 = *(const float4*)(node_w + (size_t)n * 1024 + (size_t)r * 32 + t * 4);
    float p = w4.x * a4.x + w4.y * a4.y + w4.z * a4.z + w4.w * a4.w;
    #pragma unroll
    for (int m = 1; m <= 4; m <<= 1) p += __shfl_xor(p, m);
    if (t == 0) {
        float y = p + node_b[(size_t)n * DD + r];
        y = fmaxf(y, 0.0f) + in_feat[(size_t)n * DD + r];
        ys[r] = y;
    }
    __syncthreads();
    if (tid < 64) {
        const float y = (tid < DD) ? ys[tid] : 0.0f;
        float sum = y;
        #pragma unroll
        for (int m = 1; m <= 32; m <<= 1) sum += __shfl_xor(sum, m);
        const float mu = sum * (1.0f / DD);
        const float dy = (tid < DD) ? (y - mu) : 0.0f;
        float s2 = dy * dy;
        #pragma unroll
        for (int m = 1; m <= 32; m <<= 1) s2 += __shfl_xor(s2, m);
        const float var = s2 * (1.0f / DD);
        if (tid < DD) {
            out[(size_t)n * DD + tid] =
                dy * rsqrtf(var + 1e-5f) * ln_g[tid] + ln_b[tid];
        }
    }
}

extern "C" void kernel_launch(void* const* d_in, const int* in_sizes, int n_in,
                              void* d_out, int out_size, void* d_ws, size_t ws_size,
                              hipStream_t stream) {
    const float* in_feat = (const float*)d_in[0];
    const float* query   = (const float*)d_in[1];
    const float* skw     = (const float*)d_in[2];
    const float* dkw     = (const float*)d_in[3];
    const float* skb     = (const float*)d_in[4];
    const float* dkb     = (const float*)d_in[5];
    const float* svw     = (const float*)d_in[6];
    const float* dvw     = (const float*)d_in[7];
    const float* svb     = (const float*)d_in[8];
    const float* dvb     = (const float*)d_in[9];
    const float* node_w  = (const float*)d_in[10];
    const float* node_b  = (const float*)d_in[11];
    const float* ln_g    = (const float*)d_in[12];
    const float* ln_b    = (const float*)d_in[13];
    const int*   src     = (const int*)d_in[14];
    const int*   dst     = (const int*)d_in[15];

    const int N = in_sizes[0] / DD;     // 10000
    const int E = in_sizes[14];         // 50000
    const int NH = N * HH, ND = N * DD;
    const int EH = E * HH, ED = E * DD;

    // d_out layout (return order): out[N,32], K[E,32], V[E,32], attn[E,4]
    float* out_node = (float*)d_out;
    float* Kout     = out_node + (size_t)N * DD;
    float* Vout     = Kout + (size_t)E * DD;
    float* attn_out = Vout + (size_t)E * DD;

    // workspace: score[E*4] | ex[E*4] | smax[N*4] | ssum[N*4] | agg[N*32]
    float* ws    = (float*)d_ws;
    float* score = ws;
    float* ex    = score + EH;
    float* smax  = ex + EH;
    float* ssum  = smax + NH;
    float* agg   = ssum + NH;

    // A: per-edge linears + scores (dominant HBM stream)
    edge_kernel<<<E, 256, 0, stream>>>(in_feat, query, skw, dkw, skb, dkb,
                                       svw, dvw, svb, dvb, src, dst,
                                       Kout, Vout, score, E);
    // B1: init (must run every call — ws not re-poisoned between replays)
    init_kernel<<<(ND + 255) / 256, 256, 0, stream>>>(smax, ssum, agg, NH, ND);
    // B2: segment max
    smax_kernel<<<(EH + 255) / 256, 256, 0, stream>>>(score, dst, smax, EH);
    // B3: exp + segment sum
    esum_kernel<<<(EH + 255) / 256, 256, 0, stream>>>(score, dst, smax, ex, ssum, EH);
    // B4: attn + scatter-sum into agg
    attn_agg_kernel<<<(ED + 255) / 256, 256, 0, stream>>>(ex, ssum, dst, Vout,
                                                          attn_out, agg, ED);
    // C: per-node linear + relu + residual + LayerNorm
    node_kernel<<<N, 256, 0, stream>>>(in_feat, node_w, node_b, agg,
                                       ln_g, ln_b, out_node, N);
}